// Round 9
// baseline (40.229 us; speedup 1.0000x reference)
//
#include <hip/hip_runtime.h>
#include <stdint.h>

#define HH 2048
#define WW 2048
#define NPIX (HH*WW)
#define TS 64
#define NBPX 16          // block pairs in x (each block owns 2 adjacent tiles)
#define NBY 32
#define NBLK (NBPX*NBY)  // 512 persistent blocks
#define HR (TS+8)        // 72 halo'd rows
#define QW 18            // quads per halo'd row
#define BST 24           // bmask row stride (18 nibble-bytes + 6 pad)
#define MW 3             // packed mask words per halo'd row (72 bits)

// In-flight register staging for one tile (15 float4 = 60 VGPR while pipelined)
struct Loads {
    float4 a0,a1,b0,b1,c0,c1,d0,d1,e0,e1;  // interior: 5 planes x 2 quads
    float4 ra,rb,rc,rd,re;                  // ring task (threads < 272)
    int col0;
};

__device__ __forceinline__ void issue_tile(const float4* __restrict__ t4,
    int gx0, int gy0, int t, int r, int xg, Loads& L)
{
    int qb = (gy0 + r) * (WW / 4) + (gx0 >> 2) + xg * 2;
    L.a0 = t4[qb];                   L.a1 = t4[qb + 1];
    L.b0 = t4[qb + NPIX/4];          L.b1 = t4[qb + 1 + NPIX/4];
    L.c0 = t4[qb + 2*(NPIX/4)];      L.c1 = t4[qb + 1 + 2*(NPIX/4)];
    L.d0 = t4[qb + 3*(NPIX/4)];      L.d1 = t4[qb + 1 + 3*(NPIX/4)];
    L.e0 = t4[qb + 4*(NPIX/4)];      L.e1 = t4[qb + 1 + 4*(NPIX/4)];
    if (t < 272) {                   // ring: 8 full halo rows + 64x{left,right}
        int hy, q;
        if (t < 144) { int h = t / QW; q = t - h * QW; hy = (h < 4) ? h : h + 64; }
        else         { int j = t - 144; hy = 4 + (j >> 1); q = (j & 1) ? (QW - 1) : 0; }
        int gy = gy0 - 4 + hy; gy = min(max(gy, 0), HH - 1);      // row edge-clamp
        int col0 = gx0 - 4 + 4 * q;
        int qx = col0 >> 2; qx = min(max(qx, 0), WW / 4 - 1);     // col quad clamp
        int rqb = gy * (WW / 4) + qx;
        L.ra = t4[rqb];               L.rb = t4[rqb + NPIX/4];
        L.rc = t4[rqb + 2*(NPIX/4)];  L.rd = t4[rqb + 3*(NPIX/4)];
        L.re = t4[rqb + 4*(NPIX/4)];
        L.col0 = col0;
    }
}

__device__ __forceinline__ void pack_tile(uint8_t* bmask, int t, int r, int xg,
    const Loads& L, uint32_t& fwl, uint32_t& fwh)
{
    float f0 = L.a0.x+L.b0.x+L.c0.x+L.d0.x+L.e0.x, f1 = L.a0.y+L.b0.y+L.c0.y+L.d0.y+L.e0.y;
    float f2 = L.a0.z+L.b0.z+L.c0.z+L.d0.z+L.e0.z, f3 = L.a0.w+L.b0.w+L.c0.w+L.d0.w+L.e0.w;
    float f4 = L.a1.x+L.b1.x+L.c1.x+L.d1.x+L.e1.x, f5 = L.a1.y+L.b1.y+L.c1.y+L.d1.y+L.e1.y;
    float f6 = L.a1.z+L.b1.z+L.c1.z+L.d1.z+L.e1.z, f7 = L.a1.w+L.b1.w+L.c1.w+L.d1.w+L.e1.w;
    fwl = (uint32_t)f0 | ((uint32_t)f1 << 8) | ((uint32_t)f2 << 16) | ((uint32_t)f3 << 24);
    fwh = (uint32_t)f4 | ((uint32_t)f5 << 8) | ((uint32_t)f6 << 16) | ((uint32_t)f7 << 24);
    uint32_t nib0 = (f0!=0.f?1u:0u)|(f1!=0.f?2u:0u)|(f2!=0.f?4u:0u)|(f3!=0.f?8u:0u);
    uint32_t nib1 = (f4!=0.f?1u:0u)|(f5!=0.f?2u:0u)|(f6!=0.f?4u:0u)|(f7!=0.f?8u:0u);
    bmask[(4 + r) * BST + 1 + 2 * xg] = (uint8_t)nib0;
    bmask[(4 + r) * BST + 2 + 2 * xg] = (uint8_t)nib1;
    if (t < 272) {
        int hy, q;
        if (t < 144) { int h = t / QW; q = t - h * QW; hy = (h < 4) ? h : h + 64; }
        else         { int j = t - 144; hy = 4 + (j >> 1); q = (j & 1) ? (QW - 1) : 0; }
        float g0 = L.ra.x+L.rb.x+L.rc.x+L.rd.x+L.re.x, g1 = L.ra.y+L.rb.y+L.rc.y+L.rd.y+L.re.y;
        float g2 = L.ra.z+L.rb.z+L.rc.z+L.rd.z+L.re.z, g3 = L.ra.w+L.rb.w+L.rc.w+L.rd.w+L.re.w;
        uint32_t nib = (g0!=0.f?1u:0u)|(g1!=0.f?2u:0u)|(g2!=0.f?4u:0u)|(g3!=0.f?8u:0u);
        if (L.col0 < 0)    nib = (nib & 1u) * 0xFu;    // left image edge
        if (L.col0 >= WW)  nib = (nib >> 3) * 0xFu;    // right image edge
        bmask[hy * BST + q] = (uint8_t)nib;
    }
}

// ---------------- Fused persistent kernel: 2 tiles per block, depth-2 pipeline ----------------
// issue(0); pack(0); BAR; packbits(0); BAR; issue(1); compute(0); pack(1)[vmcnt
// waits HERE, after compute]; BAR; packbits(1); BAR; compute(1). Tile-1's HBM
// latency hides under tile-0's VALU -> breaks the round-8 phase-lock.
// Code byte = ((enc-1)<<3)|fw, enc = mind2 (<=32) or 26 (unachievable = "none").
__global__ __launch_bounds__(512, 2) void fused_kernel(
    const float* __restrict__ target, const float* __restrict__ dk,
    uint8_t* __restrict__ wcode, float* __restrict__ pmin, float* __restrict__ pmax)
{
    __shared__ uint8_t  bmask[HR * BST];
    __shared__ uint32_t maskw[HR][MW];
    __shared__ uint8_t  lutm2[512];
    __shared__ float    inv_ext[65];
    __shared__ float    redmn[8], redmx[8];

    const int t   = threadIdx.x;
    const int gy0 = blockIdx.y * TS;
    const int gxA = (2 * blockIdx.x) * TS;       // tile 0
    const int gxB = gxA + TS;                    // tile 1 (adjacent: shared halo in L2)
    const float4* t4 = (const float4*)target;
    const int r  = t >> 3;                       // tile row 0..63
    const int xg = t & 7;                        // 8-px group in row

    Loads L;
    issue_tile(t4, gxA, gy0, t, r, xg, L);       // tile-0 loads in flight

    {   // tables while loads fly
        uint32_t rev = __builtin_bitreverse32((uint32_t)t) >> 23;
        uint32_t g = ((((uint32_t)t | rev) >> 4) & 0x1Fu) | 0x100u;
        lutm2[t] = (uint8_t)(__builtin_ctz(g) * __builtin_ctz(g));
    }
    if (t < 65) inv_ext[t] = 0.0f;
    if (t < HR) {                                // zero pad bytes 18..23 per row
        uint16_t* p = (uint16_t*)(bmask + t * BST + 18);
        p[0] = 0; p[1] = 0; p[2] = 0;
    }

    uint32_t fwl, fwh;
    float lmn = __int_as_float(0x7F800000);
    float lmx = 0.0f;

    #pragma unroll
    for (int it = 0; it < 2; ++it) {
        const int gx0 = it ? gxB : gxA;
        pack_tile(bmask, t, r, xg, L, fwl, fwh);        // vmcnt wait lands here
        __syncthreads();
        if (it == 0 && t < 81) {                        // fill inv table (once)
            int iy = t / 9, jx = t - (t / 9) * 9;
            int dy = iy - 4, dx = jx - 4;
            int d2 = dy * dy + dx * dx;
            if (d2 != 0) inv_ext[d2] = 1.0f / (dk[t] / (1.0f + 1e-10f) + 1e-10f);
        }
        if (t < HR * MW) {                              // nibble -> bit pack
            int hy = t / MW, ws = t - (t / MW) * MW;
            uint32_t v0 = *(const uint32_t*)(bmask + hy * BST + 8 * ws);
            uint32_t v1 = *(const uint32_t*)(bmask + hy * BST + 8 * ws + 4);
            v0 = (v0 | (v0 >> 4)) & 0x00FF00FFu; v0 = (v0 | (v0 >> 8)) & 0xFFFFu;
            v1 = (v1 | (v1 >> 4)) & 0x00FF00FFu; v1 = (v1 | (v1 >> 8)) & 0xFFFFu;
            maskw[hy][ws] = v0 | (v1 << 16);
        }
        __syncthreads();
        if (it == 0)
            issue_tile(t4, gxB, gy0, t, r, xg, L);      // tile-1 loads under compute(0)

        // ---- compute + code store (identical math to round 8; bit-exact) ----
        const int wsel = xg >> 2;
        const uint32_t sh = (uint32_t)((8 * xg) & 31);
        uint32_t wrow[9];
        #pragma unroll
        for (int k = 0; k < 9; ++k) {
            uint64_t v = (((uint64_t)maskw[r + k][wsel + 1]) << 32) | maskw[r + k][wsel];
            wrow[k] = (uint32_t)(v >> sh);
        }
        uint32_t orx[4], andx[4];
        #pragma unroll
        for (int k = 1; k <= 4; ++k) {
            orx[k-1]  = wrow[4 - k] | wrow[4 + k];
            andx[k-1] = wrow[4 - k] & wrow[4 + k];
        }
        uint32_t outb0 = 0, outb1 = 0;
        #pragma unroll
        for (int j = 0; j < 8; ++j) {
            uint32_t craw = (wrow[4] >> (4 + j)) & 1u;
            uint32_t cm = 0u - craw;
            uint32_t x0 = ((wrow[4] ^ cm) >> j) & 0x1FFu;
            uint32_t d2m = (uint32_t)lutm2[x0];
            #pragma unroll
            for (int k = 1; k <= 4; ++k) {
                uint32_t sel = craw ? andx[k-1] : orx[k-1];
                uint32_t x = ((sel ^ cm) >> j) & 0x1FFu;
                uint32_t d2 = (uint32_t)lutm2[x] + (uint32_t)(k * k);
                d2m = min(d2m, d2);
            }
            float contour = inv_ext[d2m];
            uint32_t enc = (d2m > 32u) ? 26u : d2m;
            uint32_t fwj = (j < 4 ? (fwl >> (8 * j)) : (fwh >> (8 * (j - 4)))) & 0xFFu;
            uint32_t code = ((enc - 1u) << 3) | fwj;
            if (j < 4) outb0 |= code << (8 * j);
            else       outb1 |= code << (8 * (j - 4));
            float wv = (float)fwj + contour;
            wv = wv * wv;
            lmn = fminf(lmn, wv);
            lmx = fmaxf(lmx, wv);
        }
        uint2 ob; ob.x = outb0; ob.y = outb1;
        *(uint2*)(wcode + (gy0 + r) * WW + gx0 + 8 * xg) = ob;
    }

    // block reduce over BOTH tiles -> one plain store pair (no same-addr atomics)
    #pragma unroll
    for (int off = 32; off > 0; off >>= 1) {
        lmn = fminf(lmn, __shfl_xor(lmn, off));
        lmx = fmaxf(lmx, __shfl_xor(lmx, off));
    }
    if ((t & 63) == 0) { redmn[t >> 6] = lmn; redmx[t >> 6] = lmx; }
    __syncthreads();
    if (t == 0) {
        float mn = redmn[0], mx = redmx[0];
        #pragma unroll
        for (int i = 1; i < 8; ++i) { mn = fminf(mn, redmn[i]); mx = fmaxf(mx, redmx[i]); }
        int bid = blockIdx.y * NBPX + blockIdx.x;
        pmin[bid] = mn;
        pmax[bid] = mx;
    }
}

// ---------------- Kernel C: redundant partial-reduce + LUT decode + normalize ----------------
__global__ __launch_bounds__(256) void norm_kernel(
    const uint8_t* __restrict__ wcode, const float* __restrict__ dk,
    const float* __restrict__ pmin, const float* __restrict__ pmax,
    float* __restrict__ out)
{
    __shared__ float ct[33];
    __shared__ float wlut[256];
    __shared__ float smn[4], smx[4];
    const int t = threadIdx.x;

    if (t < 33) ct[t] = 0.0f;
    float mn0 = fminf(pmin[t], pmin[t + 256]);   // 512 partials
    float mx0 = fmaxf(pmax[t], pmax[t + 256]);
    __syncthreads();
    if (t < 81) {
        int iy = t / 9, jx = t - (t / 9) * 9;
        int dy = iy - 4, dx = jx - 4;
        int d2 = dy * dy + dx * dx;
        if (d2 != 0) ct[d2] = 1.0f / (dk[t] / (1.0f + 1e-10f) + 1e-10f);
    }
    __syncthreads();
    {   // decode LUT: identical arithmetic to fused kernel -> bit-exact
        float wv = (float)(t & 7) + ct[(t >> 3) + 1];
        wlut[t] = wv * wv;
    }
    float mn = mn0, mx = mx0;
    #pragma unroll
    for (int off = 32; off > 0; off >>= 1) {
        mn = fminf(mn, __shfl_xor(mn, off));
        mx = fmaxf(mx, __shfl_xor(mx, off));
    }
    if ((t & 63) == 0) { smn[t >> 6] = mn; smx[t >> 6] = mx; }
    __syncthreads();
    mn = fminf(fminf(smn[0], smn[1]), fminf(smn[2], smn[3]));
    mx = fmaxf(fmaxf(smx[0], smx[1]), fmaxf(smx[2], smx[3]));
    const float rden = 1.0f / (mx - mn + 1e-10f);

    const int i = blockIdx.x * 256 + t;          // 8-px group id
    uint2 cb = ((const uint2*)wcode)[i];
    uint32_t b0 = cb.x, b1 = cb.y;
    float4 o0, o1;
    o0.x = (b0 & 7u)         ? (wlut[b0 & 0xFFu] - mn) * rden         : 0.0f;
    o0.y = ((b0 >> 8) & 7u)  ? (wlut[(b0 >> 8) & 0xFFu] - mn) * rden  : 0.0f;
    o0.z = ((b0 >> 16) & 7u) ? (wlut[(b0 >> 16) & 0xFFu] - mn) * rden : 0.0f;
    o0.w = ((b0 >> 24) & 7u) ? (wlut[b0 >> 24] - mn) * rden           : 0.0f;
    o1.x = (b1 & 7u)         ? (wlut[b1 & 0xFFu] - mn) * rden         : 0.0f;
    o1.y = ((b1 >> 8) & 7u)  ? (wlut[(b1 >> 8) & 0xFFu] - mn) * rden  : 0.0f;
    o1.z = ((b1 >> 16) & 7u) ? (wlut[(b1 >> 16) & 0xFFu] - mn) * rden : 0.0f;
    o1.w = ((b1 >> 24) & 7u) ? (wlut[b1 >> 24] - mn) * rden           : 0.0f;
    ((float4*)out)[i * 2]     = o0;
    ((float4*)out)[i * 2 + 1] = o1;
}

extern "C" void kernel_launch(void* const* d_in, const int* in_sizes, int n_in,
                              void* d_out, int out_size, void* d_ws, size_t ws_size,
                              hipStream_t stream)
{
    const float* target = (const float*)d_in[0];
    const float* dk     = (const float*)d_in[1];
    float* out = (float*)d_out;

    uint8_t* wsb = (uint8_t*)d_ws;
    uint8_t* wcode = wsb;                        // 4 MB u8 code plane
    float*   pmin  = (float*)(wsb + NPIX);       // 2 KB partial mins (512)
    float*   pmax  = pmin + NBLK;                // 2 KB partial maxs

    fused_kernel<<<dim3(NBPX, NBY), 512, 0, stream>>>(target, dk, wcode, pmin, pmax);

    norm_kernel<<<NPIX / 8 / 256, 256, 0, stream>>>(wcode, dk, pmin, pmax, out);
}

// Round 11
// 36.126 us; speedup vs baseline: 1.1136x; 1.1136x over previous
//
#include <hip/hip_runtime.h>
#include <stdint.h>

#define HH 2048
#define WW 2048
#define NPIX (HH*WW)
#define MROW (WW/32)     // 64 mask words per row
#define TS 64            // B tile 64x64
#define NBT (WW/TS)      // 32
#define NBLK (NBT*NBT)   // 1024 contour blocks (all co-resident: 4/CU x 8 waves)

// ---------------- Kernel A: fw nibble plane + bit-packed combined mask ----------------
__global__ __launch_bounds__(256) void fw_kernel(
    const float* __restrict__ target, uint16_t* __restrict__ fwnib,
    uint32_t* __restrict__ mask)
{
    __shared__ uint8_t nib[256];
    const int t = threadIdx.x;
    const int i = blockIdx.x * 256 + t;   // quad index, grid sized exactly
    const float4* t4 = (const float4*)target;
    float4 a = t4[i];
    float4 b = t4[(NPIX/4) + i];
    float4 c = t4[2*(NPIX/4) + i];
    float4 d = t4[3*(NPIX/4) + i];
    float4 e = t4[4*(NPIX/4) + i];
    uint32_t f0 = (uint32_t)(a.x + b.x + c.x + d.x + e.x);
    uint32_t f1 = (uint32_t)(a.y + b.y + c.y + d.y + e.y);
    uint32_t f2 = (uint32_t)(a.z + b.z + c.z + d.z + e.z);
    uint32_t f3 = (uint32_t)(a.w + b.w + c.w + d.w + e.w);
    fwnib[i] = (uint16_t)(f0 | (f1 << 4) | (f2 << 8) | (f3 << 12));   // 2 MB plane
    nib[t] = (uint8_t)((f0 ? 1u : 0u) | (f1 ? 2u : 0u) | (f2 ? 4u : 0u) | (f3 ? 8u : 0u));
    __syncthreads();
    if (t < 32) {
        const uint8_t* p = nib + t * 8;
        uint32_t w = 0;
        #pragma unroll
        for (int k = 0; k < 8; ++k) w |= (uint32_t)p[k] << (4 * k);
        mask[blockIdx.x * 32 + t] = w;   // 1024 consecutive pixels per block = 32 words
    }
}

// ---------------- Kernel B: contour -> byte code, per-block min/max ----------------
// 64x64 tile, 512 threads; thread = (row r=t>>3, 8-px group xg=t&7).
// Code byte = ((enc-1)<<3)|fw, enc = mind2 (<=32) or 26 ("none"; 26 = a^2+b^2
// unachievable for a,b<=4). Identical math to round 6 (bit-exact proven).
// ROUND-10 BUG FIX: halo row base is gx0-32, so pos = 8*xg+28 and
// wsel = pos>>5 (NOT xg>>2, which matched round 6's gx0-4 base layout).
__global__ __launch_bounds__(512) void contour_kernel(
    const uint16_t* __restrict__ fwnib, const uint32_t* __restrict__ mask,
    const float* __restrict__ dk,
    uint8_t* __restrict__ wcode, float* __restrict__ pmin, float* __restrict__ pmax)
{
    __shared__ uint32_t maskw[TS + 8][4];   // 72 halo rows x 128 bits (gx0-32..gx0+95)
    __shared__ uint8_t  lutm2[512];         // 9-bit diff-mask -> min|dx|^2 (8 -> 64)
    __shared__ float    inv_ext[65];        // d^2 -> 1/dist, 0 if unachievable/none(64)
    __shared__ float    redmn[8], redmx[8];

    const int t   = threadIdx.x;
    const int gx0 = blockIdx.x * TS;
    const int gy0 = blockIdx.y * TS;
    const int r   = t >> 3;                 // tile row 0..63
    const int xg  = t & 7;                  // 8-px group in row
    const int gy  = gy0 + r;
    const int gxb = gx0 + 8 * xg;

    // phase 0: issue memory early (halo words + own fw dword), tables under latency
    const int w0 = gx0 >> 5;
    if (t < (TS + 8) * 4) {                 // 288 halo words, one per thread
        int hr = t >> 2, wc = t & 3;
        int hgy = gy0 - 4 + hr; hgy = min(max(hgy, 0), HH - 1);
        const uint32_t* rowp = mask + hgy * MROW;
        int wi = w0 - 1 + wc;
        uint32_t v;
        if (wi < 0)            v = (rowp[0] & 1u) ? 0xFFFFFFFFu : 0u;        // left clamp
        else if (wi > MROW-1)  v = (rowp[MROW-1] >> 31) ? 0xFFFFFFFFu : 0u;  // right clamp
        else                   v = rowp[wi];
        maskw[hr][wc] = v;
    }
    const uint32_t fwd = *(const uint32_t*)((const uint8_t*)fwnib + gy * (WW/2) + (gxb >> 1));
    {   // one LUT entry per thread (512 exact)
        uint32_t rev = __builtin_bitreverse32((uint32_t)t) >> 23;     // dx -> -dx
        uint32_t g = ((((uint32_t)t | rev) >> 4) & 0x1Fu) | 0x100u;
        uint32_t mk = (uint32_t)__builtin_ctz(g);                     // min|dx| or 8
        lutm2[t] = (uint8_t)(mk * mk);
    }
    if (t < 65) inv_ext[t] = 0.0f;
    __syncthreads();
    if (t < 81) {                           // fill achievable entries from dk
        int iy = t / 9, jx = t - (t / 9) * 9;
        int dy = iy - 4, dx = jx - 4;
        int d2 = dy * dy + dx * dx;
        if (d2 != 0) inv_ext[d2] = 1.0f / (dk[t] / (1.0f + 1e-10f) + 1e-10f);
    }
    __syncthreads();

    // phase C: contour + code + min/max
    const int pos  = 8 * xg + 28;           // bit of (gxb-4) within 128-bit halo row
    const int wsel = pos >> 5;              // FIXED (was xg>>2)
    const uint32_t sh = (uint32_t)(pos & 31);
    uint32_t wrow[9];                       // bit i = col gxb-4+i (after shift)
    #pragma unroll
    for (int k = 0; k < 9; ++k) {
        uint64_t v = (((uint64_t)maskw[r + k][wsel + 1]) << 32) | maskw[r + k][wsel];
        wrow[k] = (uint32_t)(v >> sh);
    }
    // row-pair fold: diff(+k)|diff(-k) = (center ? ~(r+ & r-) : (r+ | r-)) = sel^cm
    uint32_t orx[4], andx[4];
    #pragma unroll
    for (int k = 1; k <= 4; ++k) {
        orx[k-1]  = wrow[4 - k] | wrow[4 + k];
        andx[k-1] = wrow[4 - k] & wrow[4 + k];
    }
    float lmn = __int_as_float(0x7F800000);
    float lmx = 0.0f;
    uint32_t outb0 = 0, outb1 = 0;
    #pragma unroll
    for (int j = 0; j < 8; ++j) {
        uint32_t craw = (wrow[4] >> (4 + j)) & 1u;
        uint32_t cm = 0u - craw;
        uint32_t x0 = ((wrow[4] ^ cm) >> j) & 0x1FFu;     // dy=0 (center self-0)
        uint32_t d2m = (uint32_t)lutm2[x0];               // in {1,4,9,16,64}
        #pragma unroll
        for (int k = 1; k <= 4; ++k) {
            uint32_t sel = craw ? andx[k-1] : orx[k-1];
            uint32_t x = ((sel ^ cm) >> j) & 0x1FFu;
            uint32_t d2 = (uint32_t)lutm2[x] + (uint32_t)(k * k);
            d2m = min(d2m, d2);
        }
        float contour = inv_ext[d2m];                     // 0 for "none"(64)
        uint32_t enc = (d2m > 32u) ? 26u : d2m;
        uint32_t fwj = (fwd >> (4 * j)) & 0xFu;
        uint32_t code = ((enc - 1u) << 3) | fwj;
        if (j < 4) outb0 |= code << (8 * j);
        else       outb1 |= code << (8 * (j - 4));
        float wv = (float)fwj + contour;
        wv = wv * wv;
        lmn = fminf(lmn, wv);
        lmx = fmaxf(lmx, wv);
    }
    uint2 ob; ob.x = outb0; ob.y = outb1;
    *(uint2*)(wcode + gy * WW + gxb) = ob;

    // block reduce -> one plain store pair (same-address atomics = round-2 disaster)
    #pragma unroll
    for (int off = 32; off > 0; off >>= 1) {
        lmn = fminf(lmn, __shfl_xor(lmn, off));
        lmx = fmaxf(lmx, __shfl_xor(lmx, off));
    }
    if ((t & 63) == 0) { redmn[t >> 6] = lmn; redmx[t >> 6] = lmx; }
    __syncthreads();
    if (t == 0) {
        float mn = redmn[0], mx = redmx[0];
        #pragma unroll
        for (int i = 1; i < 8; ++i) { mn = fminf(mn, redmn[i]); mx = fmaxf(mx, redmx[i]); }
        int bid = blockIdx.y * NBT + blockIdx.x;
        pmin[bid] = mn;
        pmax[bid] = mx;
    }
}

// ---------------- Kernel C: redundant partial-reduce + LUT decode + normalize ----------------
// 2048 blocks x 256 threads, 8 px/thread; w rebuilt bit-exactly from code byte.
__global__ __launch_bounds__(256) void norm_kernel(
    const uint8_t* __restrict__ wcode, const float* __restrict__ dk,
    const float* __restrict__ pmin, const float* __restrict__ pmax,
    float* __restrict__ out)
{
    __shared__ float ct[33];       // d^2 -> 1/dist (0 where none, incl code 26)
    __shared__ float wlut[256];    // code byte -> w value
    __shared__ float smn[4], smx[4];
    const int t = threadIdx.x;

    if (t < 33) ct[t] = 0.0f;
    // load the 1024 partial pairs (one float4 each) while table phases run
    const float4* pn4 = (const float4*)pmin;
    const float4* px4 = (const float4*)pmax;
    float4 a = pn4[t];
    float4 c = px4[t];
    __syncthreads();
    if (t < 81) {
        int iy = t / 9, jx = t - (t / 9) * 9;
        int dy = iy - 4, dx = jx - 4;
        int d2 = dy * dy + dx * dx;
        if (d2 != 0) ct[d2] = 1.0f / (dk[t] / (1.0f + 1e-10f) + 1e-10f);
    }
    __syncthreads();
    {   // decode LUT: identical arithmetic to contour kernel -> bit-exact
        float wv = (float)(t & 7) + ct[(t >> 3) + 1];
        wlut[t] = wv * wv;
    }
    float mn = fminf(fminf(a.x, a.y), fminf(a.z, a.w));
    float mx = fmaxf(fmaxf(c.x, c.y), fmaxf(c.z, c.w));
    #pragma unroll
    for (int off = 32; off > 0; off >>= 1) {
        mn = fminf(mn, __shfl_xor(mn, off));
        mx = fmaxf(mx, __shfl_xor(mx, off));
    }
    if ((t & 63) == 0) { smn[t >> 6] = mn; smx[t >> 6] = mx; }
    __syncthreads();
    mn = fminf(fminf(smn[0], smn[1]), fminf(smn[2], smn[3]));
    mx = fmaxf(fmaxf(smx[0], smx[1]), fmaxf(smx[2], smx[3]));
    const float rden = 1.0f / (mx - mn + 1e-10f);

    const int i = blockIdx.x * 256 + t;          // 8-px group id
    uint2 cb = ((const uint2*)wcode)[i];
    uint32_t b0 = cb.x, b1 = cb.y;
    float4 o0, o1;
    o0.x = (b0 & 7u)         ? (wlut[b0 & 0xFFu] - mn) * rden         : 0.0f;
    o0.y = ((b0 >> 8) & 7u)  ? (wlut[(b0 >> 8) & 0xFFu] - mn) * rden  : 0.0f;
    o0.z = ((b0 >> 16) & 7u) ? (wlut[(b0 >> 16) & 0xFFu] - mn) * rden : 0.0f;
    o0.w = ((b0 >> 24) & 7u) ? (wlut[b0 >> 24] - mn) * rden           : 0.0f;
    o1.x = (b1 & 7u)         ? (wlut[b1 & 0xFFu] - mn) * rden         : 0.0f;
    o1.y = ((b1 >> 8) & 7u)  ? (wlut[(b1 >> 8) & 0xFFu] - mn) * rden  : 0.0f;
    o1.z = ((b1 >> 16) & 7u) ? (wlut[(b1 >> 16) & 0xFFu] - mn) * rden : 0.0f;
    o1.w = ((b1 >> 24) & 7u) ? (wlut[b1 >> 24] - mn) * rden           : 0.0f;
    ((float4*)out)[i * 2]     = o0;
    ((float4*)out)[i * 2 + 1] = o1;
}

extern "C" void kernel_launch(void* const* d_in, const int* in_sizes, int n_in,
                              void* d_out, int out_size, void* d_ws, size_t ws_size,
                              hipStream_t stream)
{
    const float* target = (const float*)d_in[0];
    const float* dk     = (const float*)d_in[1];
    float* out = (float*)d_out;

    uint8_t* wsb = (uint8_t*)d_ws;
    uint16_t* fwnib = (uint16_t*)wsb;                        // 2 MB fw nibble plane
    uint8_t*  wcode = wsb + NPIX/2;                          // 4 MB u8 code plane
    uint32_t* mask  = (uint32_t*)(wsb + NPIX/2 + NPIX);      // 512 KB packed mask
    float*    pmin  = (float*)(wsb + NPIX/2 + NPIX + NPIX/8);// 4 KB partial mins
    float*    pmax  = pmin + NBLK;                           // 4 KB partial maxs

    fw_kernel<<<NPIX / 4 / 256, 256, 0, stream>>>(target, fwnib, mask);

    contour_kernel<<<dim3(NBT, NBT), 512, 0, stream>>>(fwnib, mask, dk, wcode, pmin, pmax);

    norm_kernel<<<NPIX / 8 / 256, 256, 0, stream>>>(wcode, dk, pmin, pmax, out);
}